// Round 5
// baseline (2623.547 us; speedup 1.0000x reference)
//
#include <hip/hip_runtime.h>
#include <hip/hip_bf16.h>
#include <hip/hip_fp16.h>

// Problem constants (match reference)
#define NN 100000
#define EE 1600000
#define INF_DIM 128
#define NHEAD 4
#define HDIM 32
#define NEG_SLOPE 0.2f

// dst-range binning (8 XCDs); NN = 8 * 12500 exactly
#define NRANGE 8
#define RNODES 12500
#define RCAP 210000  // >= E/8 + 24 sigma slack

typedef __attribute__((ext_vector_type(8))) short short8;
typedef __attribute__((ext_vector_type(4))) float floatx4;

__device__ __forceinline__ unsigned short f2bf(float x) {
  union { float f; unsigned int u; } c;
  c.f = x;
  const unsigned int r = c.u + 0x7fffu + ((c.u >> 16) & 1u);  // RNE
  return (unsigned short)(r >> 16);
}
// native packed fp32->bf16 convert (gfx950): D = {bf16(hi), bf16(lo)}
__device__ __forceinline__ unsigned int cvtpk_bf16(float lo, float hi) {
  unsigned int r;
  asm("v_cvt_pk_bf16_f32 %0, %1, %2" : "=v"(r) : "v"(lo), "v"(hi));
  return r;
}
__device__ __forceinline__ unsigned int packh2(float a, float b) {
  const __half ha = __float2half(a), hb = __float2half(b);
  const unsigned short ua = *(const unsigned short*)&ha;
  const unsigned short ub = *(const unsigned short*)&hb;
  return (unsigned int)ua | ((unsigned int)ub << 16);
}
// select fp16 weight for this lane's head out of packed {y=h01, z=h23}
__device__ __forceinline__ float pickw(const int4 e, const int head) {
  const unsigned int d = (head & 2) ? (unsigned int)e.z : (unsigned int)e.y;
  const unsigned short us =
      (head & 1) ? (unsigned short)(d >> 16) : (unsigned short)(d & 0xffffu);
  const __half h = *(const __half*)&us;
  return __half2float(h);
}
// fma 8 fp16 features (one uint4 = 4 half2) into acc[8] with scalar weight c
// (half2->float2 + fmaf fuses to v_fma_mix_f32)
__device__ __forceinline__ void accum8h(const uint4 g, const float c,
                                        float* acc) {
  union { uint4 u; __half2 h[4]; } v;
  v.u = g;
#pragma unroll
  for (int j = 0; j < 4; ++j) {
    const float2 f = __half22float2(v.h[j]);
    acc[2 * j] = fmaf(c, f.x, acc[2 * j]);
    acc[2 * j + 1] = fmaf(c, f.y, acc[2 * j + 1]);
  }
}

// ---------------------------------------------------------------------------
// MFMA GEMM: C[M,128] = A[M,128] @ W[128,128]^T (+bias), W16 bf16 row-major
// [o][k] (pre-converted). A input: fp32 (Af) or bf16 (Ab). Output: fp16 (Ch),
// or fp32+bias (Cf). Block = 64 rows x 128 cols, 4 waves; K=128 in LDS.
// Optional fused epilogue (a_s!=null): per-head attention dots from the fp32
// accumulators via 16 FMA/row + shfl_xor(1..8) intra-16 tree.
// ---------------------------------------------------------------------------
#define LDA 136

__global__ __launch_bounds__(256) void gemm_mfma(
    const float* __restrict__ Af, const unsigned short* __restrict__ Ab,
    const unsigned short* __restrict__ W16, const float* __restrict__ bias,
    unsigned short* __restrict__ Ch, float* __restrict__ Cf,
    const float* __restrict__ att_src, const float* __restrict__ att_dst,
    float* __restrict__ a_s, float* __restrict__ a_d, int M) {
  __shared__ unsigned short sA[64 * LDA];   // [m][k]
  __shared__ unsigned short sW[128 * LDA];  // [o][k] == B^T
  const int tid = threadIdx.x;
  const int m0 = blockIdx.x * 64;

  {  // W stage: pure bf16 copy, 64 shorts (8 x uint4) per thread
    const int r = tid >> 1;
    const int c0 = (tid & 1) * 64;
#pragma unroll
    for (int j = 0; j < 8; ++j) {
      *(uint4*)&sW[r * LDA + c0 + j * 8] =
          *(const uint4*)&W16[r * 128 + c0 + j * 8];
    }
  }
  {
    const int r = tid >> 2;
    const int gm = m0 + r;
    const int c0 = (tid & 3) * 32;
    if (gm < M) {
      if (Af) {
#pragma unroll
        for (int j = 0; j < 8; ++j) {
          const float4 v = *(const float4*)&Af[(size_t)gm * 128 + c0 + j * 4];
          uint2 u;
          u.x = cvtpk_bf16(v.x, v.y);
          u.y = cvtpk_bf16(v.z, v.w);
          *(uint2*)&sA[r * LDA + c0 + j * 4] = u;
        }
      } else {
#pragma unroll
        for (int j = 0; j < 4; ++j) {
          const uint4 v = *(const uint4*)&Ab[(size_t)gm * 128 + c0 + j * 8];
          *(uint4*)&sA[r * LDA + c0 + j * 8] = v;
        }
      }
    } else {
#pragma unroll
      for (int j = 0; j < 4; ++j) {
        uint4 z;
        z.x = z.y = z.z = z.w = 0u;
        *(uint4*)&sA[r * LDA + c0 + j * 8] = z;
      }
    }
  }
  __syncthreads();

  const int wv = tid >> 6;
  const int lane = tid & 63;
  const int l16 = lane & 15;
  const int quad = lane >> 4;

  floatx4 acc[8];
#pragma unroll
  for (int i = 0; i < 8; ++i) acc[i] = (floatx4){0.f, 0.f, 0.f, 0.f};

  const unsigned short* aRow = &sA[(wv * 16 + l16) * LDA + quad * 8];
#pragma unroll
  for (int kc = 0; kc < 4; ++kc) {
    const short8 afrag = *(const short8*)(aRow + kc * 32);
#pragma unroll
    for (int nt = 0; nt < 8; ++nt) {
      const short8 bfrag =
          *(const short8*)&sW[(nt * 16 + l16) * LDA + kc * 32 + quad * 8];
      acc[nt] =
          __builtin_amdgcn_mfma_f32_16x16x32_bf16(afrag, bfrag, acc[nt], 0, 0, 0);
    }
  }

  const int mrow = m0 + wv * 16 + quad * 4;
#pragma unroll
  for (int nt = 0; nt < 8; ++nt) {
    const int col = nt * 16 + l16;
    const float bv = Cf ? bias[col] : 0.f;
#pragma unroll
    for (int r = 0; r < 4; ++r) {
      const int gm = mrow + r;
      if (gm < M) {
        const float v = acc[nt][r];
        if (Ch) {
          const __half hh = __float2half(v);
          Ch[(size_t)gm * 128 + col] = *(const unsigned short*)&hh;
        } else {
          Cf[(size_t)gm * 128 + col] = v + bv;
        }
      }
    }
  }

  // fused attention-dot epilogue (gemm1 only)
  if (a_s) {
    float avs[8], avd[8];
#pragma unroll
    for (int nt = 0; nt < 8; ++nt) {
      avs[nt] = att_src[nt * 16 + l16];  // flat [h*32+d], col = nt*16+l16
      avd[nt] = att_dst[nt * 16 + l16];
    }
#pragma unroll
    for (int r = 0; r < 4; ++r) {
      float ps0 = acc[0][r] * avs[0] + acc[1][r] * avs[1];
      float ps1 = acc[2][r] * avs[2] + acc[3][r] * avs[3];
      float ps2 = acc[4][r] * avs[4] + acc[5][r] * avs[5];
      float ps3 = acc[6][r] * avs[6] + acc[7][r] * avs[7];
      float pd0 = acc[0][r] * avd[0] + acc[1][r] * avd[1];
      float pd1 = acc[2][r] * avd[2] + acc[3][r] * avd[3];
      float pd2 = acc[4][r] * avd[4] + acc[5][r] * avd[5];
      float pd3 = acc[6][r] * avd[6] + acc[7][r] * avd[7];
#pragma unroll
      for (int off = 1; off < 16; off <<= 1) {
        ps0 += __shfl_xor(ps0, off);
        ps1 += __shfl_xor(ps1, off);
        ps2 += __shfl_xor(ps2, off);
        ps3 += __shfl_xor(ps3, off);
        pd0 += __shfl_xor(pd0, off);
        pd1 += __shfl_xor(pd1, off);
        pd2 += __shfl_xor(pd2, off);
        pd3 += __shfl_xor(pd3, off);
      }
      const int gm = mrow + r;
      if (gm < M) {
        const int hs = l16 & 3;
        float vs = ps0;
        if (hs == 1) vs = ps1;
        if (hs == 2) vs = ps2;
        if (hs == 3) vs = ps3;
        float vd = pd0;
        if (hs == 1) vd = pd1;
        if (hs == 2) vd = pd2;
        if (hs == 3) vd = pd3;
        if (l16 < 4)
          a_s[gm * 4 + hs] = vs;
        else if (l16 < 8)
          a_d[gm * 4 + hs] = vd;
      }
    }
  }
}

// ---------------------------------------------------------------------------
// P0: dst histogram + dst-range binning (+ one-shot fp32->bf16 weight
// conversion in the first 8192 threads). Each edge is packed into 4 B
// {src:17b, dst_local:14b} and appended to its range list via wave-ballot
// compaction: one atomicAdd per wave per non-empty range, compacted stores.
// ---------------------------------------------------------------------------
__global__ void hist_bin_kernel(const int* __restrict__ src,
                                const int* __restrict__ dst,
                                int* __restrict__ deg,
                                unsigned int* __restrict__ rangebuf,
                                int* __restrict__ rangecnt,
                                const float* __restrict__ Wg,
                                const float* __restrict__ Wl,
                                unsigned short* __restrict__ Wg16,
                                unsigned short* __restrict__ Wl16) {
  const int i = blockIdx.x * blockDim.x + threadIdx.x;
  if (i < 8192) {  // 2 matrices x 4096 float4
    const int m = i >> 12;
    const int j = i & 4095;
    const float4 v = m ? ((const float4*)Wl)[j] : ((const float4*)Wg)[j];
    ushort4 u;
    u.x = f2bf(v.x);
    u.y = f2bf(v.y);
    u.z = f2bf(v.z);
    u.w = f2bf(v.w);
    if (m)
      ((ushort4*)Wl16)[j] = u;
    else
      ((ushort4*)Wg16)[j] = u;
  }
  // grid covers EE exactly (EE % 256 == 0) -> all lanes edge-valid
  const int lane = threadIdx.x & 63;
  const int s = src[i];
  const int d = dst[i];
  atomicAdd(&deg[d], 1);
  const int r = d / RNODES;
  const unsigned int rec =
      (unsigned int)s | ((unsigned int)(d - r * RNODES) << 17);
#pragma unroll
  for (int k = 0; k < NRANGE; ++k) {
    const unsigned long long m = __ballot(r == k);
    if (m) {
      int base = 0;
      if (lane == 0) base = atomicAdd(&rangecnt[k], __popcll(m));
      base = __shfl(base, 0, 64);
      if (r == k) {
        const int pos = base + (int)__popcll(m & ((1ull << lane) - 1ull));
        rangebuf[(size_t)k * RCAP + pos] = rec;
      }
    }
  }
}

__global__ __launch_bounds__(256) void alloc_kernel(const int* __restrict__ deg,
                                                    int* __restrict__ rowptr,
                                                    int* __restrict__ cur,
                                                    int* __restrict__ counter) {
  const int i = blockIdx.x * blockDim.x + threadIdx.x;
  const int lane = threadIdx.x & 63;
  const int d = (i < NN) ? deg[i] : 0;
  int s = d;
#pragma unroll
  for (int off = 1; off < 64; off <<= 1) {
    const int v = __shfl_up(s, off, 64);
    if (lane >= off) s += v;
  }
  const int total = __shfl(s, 63, 64);
  int base = 0;
  if (lane == 63) base = atomicAdd(counter, total);
  base = __shfl(base, 63, 64);
  const int p = base + s - d;
  if (i < NN) {
    rowptr[i] = p;
    cur[i] = p;
  }
}

// ---------------------------------------------------------------------------
// P1: fine scatter. Block b serves dst-range k = b & 7, so (with the bid%8
// XCD round-robin) all partial-line writes to range k's contiguous ~3.2 MB
// ebuf span come from one XCD and stay resident in its L2 -> one
// fetch+writeback per line instead of four. Emits 16 B records
// {src, fp16 w01, fp16 w23, 0} at CSR positions (format unchanged).
// ---------------------------------------------------------------------------
#define P1B 98  // blocks per range

__global__ __launch_bounds__(256) void scatter_fine(
    const unsigned int* __restrict__ rangebuf, const int* __restrict__ rangecnt,
    const float* __restrict__ a_s, const float* __restrict__ a_d,
    int* __restrict__ cur, int4* __restrict__ ebuf) {
  const int k = blockIdx.x & 7;
  const int chunk = blockIdx.x >> 3;
  const int cnt = rangecnt[k];
  const unsigned int* rb = rangebuf + (size_t)k * RCAP;
  for (int j = chunk * 256 + (int)threadIdx.x; j < cnt; j += P1B * 256) {
    const unsigned int rec = rb[j];
    const int s = (int)(rec & 0x1FFFFu);
    const int d = k * RNODES + (int)(rec >> 17);
    const int p = atomicAdd(&cur[d], 1);
    const float4 as = *(const float4*)&a_s[s * 4];
    const float4 ad = *(const float4*)&a_d[d * 4];
    float4 l;
    l.x = as.x + ad.x;
    l.y = as.y + ad.y;
    l.z = as.z + ad.z;
    l.w = as.w + ad.w;
    l.x = l.x > 0.f ? l.x : NEG_SLOPE * l.x;
    l.y = l.y > 0.f ? l.y : NEG_SLOPE * l.y;
    l.z = l.z > 0.f ? l.z : NEG_SLOPE * l.z;
    l.w = l.w > 0.f ? l.w : NEG_SLOPE * l.w;
    int4 e;
    e.x = s;
    e.y = (int)packh2(__expf(l.x), __expf(l.y));
    e.z = (int)packh2(__expf(l.z), __expf(l.w));
    e.w = 0;
    ebuf[p] = e;
  }
}

// ---------------------------------------------------------------------------
// Aggregate: one wave per destination node, quarter-wave per edge.
// q = lane>>4 (edge slot), f = lane&15 (feature group, head = f>>2).
// 16-edge super-iteration: 4 record loads then 4 independent uint4 feature
// gathers in flight (statically unrolled), then consume. Features are fp16
// (v_fma_mix accumulate into fp32). Cross-quarter reduce via shfl_xor(16/32).
// ---------------------------------------------------------------------------
__global__ __launch_bounds__(256) void aggregate_kernel(
    const uint4* __restrict__ hbd4, const float* __restrict__ a_s,
    const float* __restrict__ a_d, const float* __restrict__ bias_gat,
    const int* __restrict__ rowptr, const int* __restrict__ deg,
    const int4* __restrict__ ebuf, uint4* __restrict__ obd4) {
  const int wave = (blockIdx.x * blockDim.x + threadIdx.x) >> 6;
  if (wave >= NN) return;
  const int lane = threadIdx.x & 63;
  const int q = lane >> 4;
  const int f = lane & 15;
  const int head = f >> 2;
  const int n = wave;

  float acc[8];
  float ds;
  {  // self loop (only quarter 0 contributes; others start at zero)
    const float l0 = a_s[n * 4 + head] + a_d[n * 4 + head];
    const float l = fmaxf(l0, NEG_SLOPE * l0);
    float cs = __expf(l);
    if (q != 0) cs = 0.f;
    union { uint4 u; __half2 h[4]; } v;
    v.u = hbd4[(size_t)n * 16 + f];
#pragma unroll
    for (int j = 0; j < 4; ++j) {
      const float2 fv = __half22float2(v.h[j]);
      acc[2 * j] = cs * fv.x;
      acc[2 * j + 1] = cs * fv.y;
    }
    ds = cs;
  }

  const int beg = rowptr[n];
  const int end = beg + deg[n];
  for (int i = beg; i < end; i += 16) {
    int4 e0, e1, e2, e3;
    {
      const int i0 = i + q, i1 = i + 4 + q, i2 = i + 8 + q, i3 = i + 12 + q;
      e0 = ebuf[i0 < end ? i0 : end - 1];
      e1 = ebuf[i1 < end ? i1 : end - 1];
      e2 = ebuf[i2 < end ? i2 : end - 1];
      e3 = ebuf[i3 < end ? i3 : end - 1];
    }
    // 4 independent feature gathers in flight
    const uint4 g0 = hbd4[(size_t)e0.x * 16 + f];
    const uint4 g1 = hbd4[(size_t)e1.x * 16 + f];
    const uint4 g2 = hbd4[(size_t)e2.x * 16 + f];
    const uint4 g3 = hbd4[(size_t)e3.x * 16 + f];
    float c0 = pickw(e0, head);
    float c1 = pickw(e1, head);
    float c2 = pickw(e2, head);
    float c3 = pickw(e3, head);
    if (i + q >= end) c0 = 0.f;
    if (i + 4 + q >= end) c1 = 0.f;
    if (i + 8 + q >= end) c2 = 0.f;
    if (i + 12 + q >= end) c3 = 0.f;
    accum8h(g0, c0, acc);
    accum8h(g1, c1, acc);
    accum8h(g2, c2, acc);
    accum8h(g3, c3, acc);
    ds += c0 + c1 + c2 + c3;
  }

  // reduce across the 4 quarters (lanes l, l^16, l^32, l^48 share f)
#pragma unroll
  for (int j = 0; j < 8; ++j) {
    acc[j] += __shfl_xor(acc[j], 16);
    acc[j] += __shfl_xor(acc[j], 32);
  }
  ds += __shfl_xor(ds, 16);
  ds += __shfl_xor(ds, 32);

  if (q == 0) {
    const float inv = 1.0f / ds;
    const float4 b0 = *(const float4*)&bias_gat[f * 8];
    const float4 b1 = *(const float4*)&bias_gat[f * 8 + 4];
    float v0 = acc[0] * inv + b0.x;
    float v1 = acc[1] * inv + b0.y;
    float v2 = acc[2] * inv + b0.z;
    float v3 = acc[3] * inv + b0.w;
    float v4 = acc[4] * inv + b1.x;
    float v5 = acc[5] * inv + b1.y;
    float v6 = acc[6] * inv + b1.z;
    float v7 = acc[7] * inv + b1.w;
    v0 = v0 > 0.f ? v0 : 0.f;
    v1 = v1 > 0.f ? v1 : 0.f;
    v2 = v2 > 0.f ? v2 : 0.f;
    v3 = v3 > 0.f ? v3 : 0.f;
    v4 = v4 > 0.f ? v4 : 0.f;
    v5 = v5 > 0.f ? v5 : 0.f;
    v6 = v6 > 0.f ? v6 : 0.f;
    v7 = v7 > 0.f ? v7 : 0.f;
    uint4 r;
    r.x = (unsigned int)f2bf(v0) | ((unsigned int)f2bf(v1) << 16);
    r.y = (unsigned int)f2bf(v2) | ((unsigned int)f2bf(v3) << 16);
    r.z = (unsigned int)f2bf(v4) | ((unsigned int)f2bf(v5) << 16);
    r.w = (unsigned int)f2bf(v6) | ((unsigned int)f2bf(v7) << 16);
    obd4[(size_t)n * 16 + f] = r;
  }
}

// ---------------------------------------------------------------------------
extern "C" void kernel_launch(void* const* d_in, const int* in_sizes, int n_in,
                              void* d_out, int out_size, void* d_ws,
                              size_t ws_size, hipStream_t stream) {
  const float* x = (const float*)d_in[0];
  const int* ei = (const int*)d_in[1];  // [2,E]: row0=src, row1=dst
  const float* W_gat = (const float*)d_in[2];
  const float* att_src = (const float*)d_in[3];
  const float* att_dst = (const float*)d_in[4];
  const float* bias_gat = (const float*)d_in[5];
  const float* W_lin = (const float*)d_in[6];
  const float* b_lin = (const float*)d_in[7];
  float* out = (float*)d_out;

  // workspace carve-up (16B aligned)
  char* ws = (char*)d_ws;
  size_t off = 0;
  unsigned short* hb = (unsigned short*)(ws + off);
  off += (size_t)NN * 128 * 2;  // 25.6 MB (fp16 features)
  unsigned short* ob = (unsigned short*)(ws + off);
  off += (size_t)NN * 128 * 2;  // 25.6 MB (bf16 aggregate out)
  float* a_s = (float*)(ws + off); off += (size_t)NN * 4 * 4;
  float* a_d = (float*)(ws + off); off += (size_t)NN * 4 * 4;
  int* deg = (int*)(ws + off); off += (size_t)NN * 4;
  int* rowptr = (int*)(ws + off); off += (size_t)(NN + 4) * 4;
  int* cur = (int*)(ws + off); off += (size_t)NN * 4;
  int* counter = (int*)(ws + off); off += 16;
  unsigned short* Wg16 = (unsigned short*)(ws + off); off += 128 * 128 * 2;
  unsigned short* Wl16 = (unsigned short*)(ws + off); off += 128 * 128 * 2;
  unsigned int* rangebuf = (unsigned int*)(ws + off);
  off += (size_t)NRANGE * RCAP * 4;  // 6.7 MB
  int* rangecnt = (int*)(ws + off); off += 32;
  int4* ebuf = (int4*)(ws + off); off += (size_t)EE * 16;  // 25.6 MB

  const int* src = ei;
  const int* dst = ei + EE;

  // CSR histogram + range binning + weight bf16 pre-convert
  hipMemsetAsync(deg, 0, (size_t)NN * 4, stream);
  hipMemsetAsync(counter, 0, 16, stream);
  hipMemsetAsync(rangecnt, 0, 32, stream);
  hist_bin_kernel<<<EE / 256, 256, 0, stream>>>(src, dst, deg, rangebuf,
                                                rangecnt, W_gat, W_lin, Wg16,
                                                Wl16);
  alloc_kernel<<<(NN + 255) / 256, 256, 0, stream>>>(deg, rowptr, cur, counter);
  // 1) hb = fp16(x @ W_gat^T) with fused a_s/a_d epilogue  [MFMA]
  gemm_mfma<<<(NN + 63) / 64, 256, 0, stream>>>(x, nullptr, Wg16, nullptr, hb,
                                                nullptr, att_src, att_dst, a_s,
                                                a_d, NN);
  // 2) XCD-aligned fine scatter (16 B records into per-range CSR spans)
  scatter_fine<<<NRANGE * P1B, 256, 0, stream>>>(rangebuf, rangecnt, a_s, a_d,
                                                 cur, ebuf);
  // 3) softmax-weighted aggregation (+bias, relu) -> bf16
  aggregate_kernel<<<(NN + 3) / 4, 256, 0, stream>>>(
      (const uint4*)hb, a_s, a_d, bias_gat, rowptr, deg, ebuf,
      (uint4*)ob);
  // 4) out = ob @ W_lin^T + b_lin  [MFMA]
  gemm_mfma<<<(NN + 63) / 64, 256, 0, stream>>>(nullptr, ob, Wl16, b_lin,
                                                nullptr, out, nullptr, nullptr,
                                                nullptr, nullptr, NN);
}

// Round 6
// 430.896 us; speedup vs baseline: 6.0886x; 6.0886x over previous
//
#include <hip/hip_runtime.h>
#include <hip/hip_bf16.h>
#include <hip/hip_fp16.h>

// Problem constants (match reference)
#define NN 100000
#define EE 1600000
#define INF_DIM 128
#define NHEAD 4
#define HDIM 32
#define NEG_SLOPE 0.2f

// dst-range partitioning for XCD-local ebuf writes (8 XCDs); NN = 8 * 12500
#define NRANGE 8
#define RNODES 12500
#define P1B 98  // blocks per range in scatter_fine

typedef __attribute__((ext_vector_type(8))) short short8;
typedef __attribute__((ext_vector_type(4))) float floatx4;

__device__ __forceinline__ unsigned short f2bf(float x) {
  union { float f; unsigned int u; } c;
  c.f = x;
  const unsigned int r = c.u + 0x7fffu + ((c.u >> 16) & 1u);  // RNE
  return (unsigned short)(r >> 16);
}
// native packed fp32->bf16 convert (gfx950): D = {bf16(hi), bf16(lo)}
__device__ __forceinline__ unsigned int cvtpk_bf16(float lo, float hi) {
  unsigned int r;
  asm("v_cvt_pk_bf16_f32 %0, %1, %2" : "=v"(r) : "v"(lo), "v"(hi));
  return r;
}
__device__ __forceinline__ unsigned int packh2(float a, float b) {
  const __half ha = __float2half(a), hb = __float2half(b);
  const unsigned short ua = *(const unsigned short*)&ha;
  const unsigned short ub = *(const unsigned short*)&hb;
  return (unsigned int)ua | ((unsigned int)ub << 16);
}
// select fp16 weight for this lane's head out of packed {y=h01, z=h23}
__device__ __forceinline__ float pickw(const int4 e, const int head) {
  const unsigned int d = (head & 2) ? (unsigned int)e.z : (unsigned int)e.y;
  const unsigned short us =
      (head & 1) ? (unsigned short)(d >> 16) : (unsigned short)(d & 0xffffu);
  const __half h = *(const __half*)&us;
  return __half2float(h);
}
// fma 8 fp16 features (one uint4 = 4 half2) into acc[8] with scalar weight c
// (half2->float2 + fmaf fuses to v_fma_mix_f32)
__device__ __forceinline__ void accum8h(const uint4 g, const float c,
                                        float* acc) {
  union { uint4 u; __half2 h[4]; } v;
  v.u = g;
#pragma unroll
  for (int j = 0; j < 4; ++j) {
    const float2 f = __half22float2(v.h[j]);
    acc[2 * j] = fmaf(c, f.x, acc[2 * j]);
    acc[2 * j + 1] = fmaf(c, f.y, acc[2 * j + 1]);
  }
}

// ---------------------------------------------------------------------------
// MFMA GEMM: C[M,128] = A[M,128] @ W[128,128]^T (+bias), W16 bf16 row-major
// [o][k] (pre-converted). A input: fp32 (Af) or bf16 (Ab). Output: fp16 (Ch),
// or fp32+bias (Cf). Block = 64 rows x 128 cols, 4 waves; K=128 in LDS.
// Optional fused epilogue (a_s!=null): per-head attention dots from the fp32
// accumulators via 16 FMA/row + shfl_xor(1..8) intra-16 tree.
// ---------------------------------------------------------------------------
#define LDA 136

__global__ __launch_bounds__(256) void gemm_mfma(
    const float* __restrict__ Af, const unsigned short* __restrict__ Ab,
    const unsigned short* __restrict__ W16, const float* __restrict__ bias,
    unsigned short* __restrict__ Ch, float* __restrict__ Cf,
    const float* __restrict__ att_src, const float* __restrict__ att_dst,
    float* __restrict__ a_s, float* __restrict__ a_d, int M) {
  __shared__ unsigned short sA[64 * LDA];   // [m][k]
  __shared__ unsigned short sW[128 * LDA];  // [o][k] == B^T
  const int tid = threadIdx.x;
  const int m0 = blockIdx.x * 64;

  {  // W stage: pure bf16 copy, 64 shorts (8 x uint4) per thread
    const int r = tid >> 1;
    const int c0 = (tid & 1) * 64;
#pragma unroll
    for (int j = 0; j < 8; ++j) {
      *(uint4*)&sW[r * LDA + c0 + j * 8] =
          *(const uint4*)&W16[r * 128 + c0 + j * 8];
    }
  }
  {
    const int r = tid >> 2;
    const int gm = m0 + r;
    const int c0 = (tid & 3) * 32;
    if (gm < M) {
      if (Af) {
#pragma unroll
        for (int j = 0; j < 8; ++j) {
          const float4 v = *(const float4*)&Af[(size_t)gm * 128 + c0 + j * 4];
          uint2 u;
          u.x = cvtpk_bf16(v.x, v.y);
          u.y = cvtpk_bf16(v.z, v.w);
          *(uint2*)&sA[r * LDA + c0 + j * 4] = u;
        }
      } else {
#pragma unroll
        for (int j = 0; j < 4; ++j) {
          const uint4 v = *(const uint4*)&Ab[(size_t)gm * 128 + c0 + j * 8];
          *(uint4*)&sA[r * LDA + c0 + j * 8] = v;
        }
      }
    } else {
#pragma unroll
      for (int j = 0; j < 4; ++j) {
        uint4 z;
        z.x = z.y = z.z = z.w = 0u;
        *(uint4*)&sA[r * LDA + c0 + j * 8] = z;
      }
    }
  }
  __syncthreads();

  const int wv = tid >> 6;
  const int lane = tid & 63;
  const int l16 = lane & 15;
  const int quad = lane >> 4;

  floatx4 acc[8];
#pragma unroll
  for (int i = 0; i < 8; ++i) acc[i] = (floatx4){0.f, 0.f, 0.f, 0.f};

  const unsigned short* aRow = &sA[(wv * 16 + l16) * LDA + quad * 8];
#pragma unroll
  for (int kc = 0; kc < 4; ++kc) {
    const short8 afrag = *(const short8*)(aRow + kc * 32);
#pragma unroll
    for (int nt = 0; nt < 8; ++nt) {
      const short8 bfrag =
          *(const short8*)&sW[(nt * 16 + l16) * LDA + kc * 32 + quad * 8];
      acc[nt] =
          __builtin_amdgcn_mfma_f32_16x16x32_bf16(afrag, bfrag, acc[nt], 0, 0, 0);
    }
  }

  const int mrow = m0 + wv * 16 + quad * 4;
#pragma unroll
  for (int nt = 0; nt < 8; ++nt) {
    const int col = nt * 16 + l16;
    const float bv = Cf ? bias[col] : 0.f;
#pragma unroll
    for (int r = 0; r < 4; ++r) {
      const int gm = mrow + r;
      if (gm < M) {
        const float v = acc[nt][r];
        if (Ch) {
          const __half hh = __float2half(v);
          Ch[(size_t)gm * 128 + col] = *(const unsigned short*)&hh;
        } else {
          Cf[(size_t)gm * 128 + col] = v + bv;
        }
      }
    }
  }

  // fused attention-dot epilogue (gemm1 only)
  if (a_s) {
    float avs[8], avd[8];
#pragma unroll
    for (int nt = 0; nt < 8; ++nt) {
      avs[nt] = att_src[nt * 16 + l16];  // flat [h*32+d], col = nt*16+l16
      avd[nt] = att_dst[nt * 16 + l16];
    }
#pragma unroll
    for (int r = 0; r < 4; ++r) {
      float ps0 = acc[0][r] * avs[0] + acc[1][r] * avs[1];
      float ps1 = acc[2][r] * avs[2] + acc[3][r] * avs[3];
      float ps2 = acc[4][r] * avs[4] + acc[5][r] * avs[5];
      float ps3 = acc[6][r] * avs[6] + acc[7][r] * avs[7];
      float pd0 = acc[0][r] * avd[0] + acc[1][r] * avd[1];
      float pd1 = acc[2][r] * avd[2] + acc[3][r] * avd[3];
      float pd2 = acc[4][r] * avd[4] + acc[5][r] * avd[5];
      float pd3 = acc[6][r] * avd[6] + acc[7][r] * avd[7];
#pragma unroll
      for (int off = 1; off < 16; off <<= 1) {
        ps0 += __shfl_xor(ps0, off);
        ps1 += __shfl_xor(ps1, off);
        ps2 += __shfl_xor(ps2, off);
        ps3 += __shfl_xor(ps3, off);
        pd0 += __shfl_xor(pd0, off);
        pd1 += __shfl_xor(pd1, off);
        pd2 += __shfl_xor(pd2, off);
        pd3 += __shfl_xor(pd3, off);
      }
      const int gm = mrow + r;
      if (gm < M) {
        const int hs = l16 & 3;
        float vs = ps0;
        if (hs == 1) vs = ps1;
        if (hs == 2) vs = ps2;
        if (hs == 3) vs = ps3;
        float vd = pd0;
        if (hs == 1) vd = pd1;
        if (hs == 2) vd = pd2;
        if (hs == 3) vd = pd3;
        if (l16 < 4)
          a_s[gm * 4 + hs] = vs;
        else if (l16 < 8)
          a_d[gm * 4 + hs] = vd;
      }
    }
  }
}

// ---------------------------------------------------------------------------
// hist + one-shot fp32->bf16 weight conversion (first 8192 threads convert
// W_gat and W_lin, 4 elements each; the rest is the dst histogram).
// ---------------------------------------------------------------------------
__global__ void hist_kernel(const int* __restrict__ dst, int* __restrict__ deg,
                            const float* __restrict__ Wg,
                            const float* __restrict__ Wl,
                            unsigned short* __restrict__ Wg16,
                            unsigned short* __restrict__ Wl16) {
  const int i = blockIdx.x * blockDim.x + threadIdx.x;
  if (i < 8192) {  // 2 matrices x 4096 float4
    const int m = i >> 12;
    const int j = i & 4095;
    const float4 v = m ? ((const float4*)Wl)[j] : ((const float4*)Wg)[j];
    ushort4 u;
    u.x = f2bf(v.x);
    u.y = f2bf(v.y);
    u.z = f2bf(v.z);
    u.w = f2bf(v.w);
    if (m)
      ((ushort4*)Wl16)[j] = u;
    else
      ((ushort4*)Wg16)[j] = u;
  }
  if (i < EE) atomicAdd(&deg[dst[i]], 1);
}

__global__ __launch_bounds__(256) void alloc_kernel(const int* __restrict__ deg,
                                                    int* __restrict__ rowptr,
                                                    int* __restrict__ cur,
                                                    int* __restrict__ counter) {
  const int i = blockIdx.x * blockDim.x + threadIdx.x;
  const int lane = threadIdx.x & 63;
  const int d = (i < NN) ? deg[i] : 0;
  int s = d;
#pragma unroll
  for (int off = 1; off < 64; off <<= 1) {
    const int v = __shfl_up(s, off, 64);
    if (lane >= off) s += v;
  }
  const int total = __shfl(s, 63, 64);
  int base = 0;
  if (lane == 63) base = atomicAdd(counter, total);
  base = __shfl(base, 63, 64);
  const int p = base + s - d;
  if (i < NN) {
    rowptr[i] = p;
    cur[i] = p;
  }
}

// ---------------------------------------------------------------------------
// Scatter (filter-scan, XCD-range-aligned): block b owns dst-range k = b&7
// (matching the bid%8 -> XCD round-robin heuristic). It streams the dst
// array (coalesced; groups of 8 blocks scan the same chunk concurrently so
// the stream is read once from HBM and L3-served to the rest) and processes
// only edges whose dst lies in its range. All partial-line ebuf writes to
// range k's contiguous ~3.2 MB CSR span thus come from one XCD and stay
// L2-resident -> 1 fetch + 1 writeback per 64 B line instead of ~4.
// Record format unchanged: {src, fp16 w01, fp16 w23, 0}.
// Correctness does NOT depend on the XCD mapping (any block-range assignment
// covers every edge exactly once); the mapping only affects locality/speed.
// ---------------------------------------------------------------------------
__global__ __launch_bounds__(256) void scatter_fine(
    const int* __restrict__ src, const int* __restrict__ dst,
    const float* __restrict__ a_s, const float* __restrict__ a_d,
    int* __restrict__ cur, int4* __restrict__ ebuf) {
  const int k = blockIdx.x & 7;
  const int chunk = blockIdx.x >> 3;
  const int dlo = k * RNODES;
  const int dhi = dlo + RNODES;
  for (int i = chunk * 256 + (int)threadIdx.x; i < EE; i += P1B * 256) {
    const int d = dst[i];
    if (d < dlo || d >= dhi) continue;
    const int s = src[i];
    const int p = atomicAdd(&cur[d], 1);
    const float4 as = *(const float4*)&a_s[s * 4];
    const float4 ad = *(const float4*)&a_d[d * 4];
    float4 l;
    l.x = as.x + ad.x;
    l.y = as.y + ad.y;
    l.z = as.z + ad.z;
    l.w = as.w + ad.w;
    l.x = l.x > 0.f ? l.x : NEG_SLOPE * l.x;
    l.y = l.y > 0.f ? l.y : NEG_SLOPE * l.y;
    l.z = l.z > 0.f ? l.z : NEG_SLOPE * l.z;
    l.w = l.w > 0.f ? l.w : NEG_SLOPE * l.w;
    int4 e;
    e.x = s;
    e.y = (int)packh2(__expf(l.x), __expf(l.y));
    e.z = (int)packh2(__expf(l.z), __expf(l.w));
    e.w = 0;
    ebuf[p] = e;
  }
}

// ---------------------------------------------------------------------------
// Aggregate: one wave per destination node, quarter-wave per edge.
// q = lane>>4 (edge slot), f = lane&15 (feature group, head = f>>2).
// 16-edge super-iteration: 4 record loads then 4 independent uint4 feature
// gathers in flight (statically unrolled), then consume. Features are fp16
// (v_fma_mix accumulate into fp32). Cross-quarter reduce via shfl_xor(16/32).
// ---------------------------------------------------------------------------
__global__ __launch_bounds__(256) void aggregate_kernel(
    const uint4* __restrict__ hbd4, const float* __restrict__ a_s,
    const float* __restrict__ a_d, const float* __restrict__ bias_gat,
    const int* __restrict__ rowptr, const int* __restrict__ deg,
    const int4* __restrict__ ebuf, uint4* __restrict__ obd4) {
  const int wave = (blockIdx.x * blockDim.x + threadIdx.x) >> 6;
  if (wave >= NN) return;
  const int lane = threadIdx.x & 63;
  const int q = lane >> 4;
  const int f = lane & 15;
  const int head = f >> 2;
  const int n = wave;

  float acc[8];
  float ds;
  {  // self loop (only quarter 0 contributes; others start at zero)
    const float l0 = a_s[n * 4 + head] + a_d[n * 4 + head];
    const float l = fmaxf(l0, NEG_SLOPE * l0);
    float cs = __expf(l);
    if (q != 0) cs = 0.f;
    union { uint4 u; __half2 h[4]; } v;
    v.u = hbd4[(size_t)n * 16 + f];
#pragma unroll
    for (int j = 0; j < 4; ++j) {
      const float2 fv = __half22float2(v.h[j]);
      acc[2 * j] = cs * fv.x;
      acc[2 * j + 1] = cs * fv.y;
    }
    ds = cs;
  }

  const int beg = rowptr[n];
  const int end = beg + deg[n];
  for (int i = beg; i < end; i += 16) {
    int4 e0, e1, e2, e3;
    {
      const int i0 = i + q, i1 = i + 4 + q, i2 = i + 8 + q, i3 = i + 12 + q;
      e0 = ebuf[i0 < end ? i0 : end - 1];
      e1 = ebuf[i1 < end ? i1 : end - 1];
      e2 = ebuf[i2 < end ? i2 : end - 1];
      e3 = ebuf[i3 < end ? i3 : end - 1];
    }
    // 4 independent feature gathers in flight
    const uint4 g0 = hbd4[(size_t)e0.x * 16 + f];
    const uint4 g1 = hbd4[(size_t)e1.x * 16 + f];
    const uint4 g2 = hbd4[(size_t)e2.x * 16 + f];
    const uint4 g3 = hbd4[(size_t)e3.x * 16 + f];
    float c0 = pickw(e0, head);
    float c1 = pickw(e1, head);
    float c2 = pickw(e2, head);
    float c3 = pickw(e3, head);
    if (i + q >= end) c0 = 0.f;
    if (i + 4 + q >= end) c1 = 0.f;
    if (i + 8 + q >= end) c2 = 0.f;
    if (i + 12 + q >= end) c3 = 0.f;
    accum8h(g0, c0, acc);
    accum8h(g1, c1, acc);
    accum8h(g2, c2, acc);
    accum8h(g3, c3, acc);
    ds += c0 + c1 + c2 + c3;
  }

  // reduce across the 4 quarters (lanes l, l^16, l^32, l^48 share f)
#pragma unroll
  for (int j = 0; j < 8; ++j) {
    acc[j] += __shfl_xor(acc[j], 16);
    acc[j] += __shfl_xor(acc[j], 32);
  }
  ds += __shfl_xor(ds, 16);
  ds += __shfl_xor(ds, 32);

  if (q == 0) {
    const float inv = 1.0f / ds;
    const float4 b0 = *(const float4*)&bias_gat[f * 8];
    const float4 b1 = *(const float4*)&bias_gat[f * 8 + 4];
    float v0 = acc[0] * inv + b0.x;
    float v1 = acc[1] * inv + b0.y;
    float v2 = acc[2] * inv + b0.z;
    float v3 = acc[3] * inv + b0.w;
    float v4 = acc[4] * inv + b1.x;
    float v5 = acc[5] * inv + b1.y;
    float v6 = acc[6] * inv + b1.z;
    float v7 = acc[7] * inv + b1.w;
    v0 = v0 > 0.f ? v0 : 0.f;
    v1 = v1 > 0.f ? v1 : 0.f;
    v2 = v2 > 0.f ? v2 : 0.f;
    v3 = v3 > 0.f ? v3 : 0.f;
    v4 = v4 > 0.f ? v4 : 0.f;
    v5 = v5 > 0.f ? v5 : 0.f;
    v6 = v6 > 0.f ? v6 : 0.f;
    v7 = v7 > 0.f ? v7 : 0.f;
    uint4 r;
    r.x = (unsigned int)f2bf(v0) | ((unsigned int)f2bf(v1) << 16);
    r.y = (unsigned int)f2bf(v2) | ((unsigned int)f2bf(v3) << 16);
    r.z = (unsigned int)f2bf(v4) | ((unsigned int)f2bf(v5) << 16);
    r.w = (unsigned int)f2bf(v6) | ((unsigned int)f2bf(v7) << 16);
    obd4[(size_t)n * 16 + f] = r;
  }
}

// ---------------------------------------------------------------------------
extern "C" void kernel_launch(void* const* d_in, const int* in_sizes, int n_in,
                              void* d_out, int out_size, void* d_ws,
                              size_t ws_size, hipStream_t stream) {
  const float* x = (const float*)d_in[0];
  const int* ei = (const int*)d_in[1];  // [2,E]: row0=src, row1=dst
  const float* W_gat = (const float*)d_in[2];
  const float* att_src = (const float*)d_in[3];
  const float* att_dst = (const float*)d_in[4];
  const float* bias_gat = (const float*)d_in[5];
  const float* W_lin = (const float*)d_in[6];
  const float* b_lin = (const float*)d_in[7];
  float* out = (float*)d_out;

  // workspace carve-up (16B aligned)
  char* ws = (char*)d_ws;
  size_t off = 0;
  unsigned short* hb = (unsigned short*)(ws + off);
  off += (size_t)NN * 128 * 2;  // 25.6 MB (fp16 features)
  unsigned short* ob = (unsigned short*)(ws + off);
  off += (size_t)NN * 128 * 2;  // 25.6 MB (bf16 aggregate out)
  float* a_s = (float*)(ws + off); off += (size_t)NN * 4 * 4;
  float* a_d = (float*)(ws + off); off += (size_t)NN * 4 * 4;
  int* deg = (int*)(ws + off); off += (size_t)NN * 4;
  int* rowptr = (int*)(ws + off); off += (size_t)(NN + 4) * 4;
  int* cur = (int*)(ws + off); off += (size_t)NN * 4;
  int* counter = (int*)(ws + off); off += 16;
  unsigned short* Wg16 = (unsigned short*)(ws + off); off += 128 * 128 * 2;
  unsigned short* Wl16 = (unsigned short*)(ws + off); off += 128 * 128 * 2;
  int4* ebuf = (int4*)(ws + off); off += (size_t)EE * 16;  // 25.6 MB

  const int* src = ei;
  const int* dst = ei + EE;

  // CSR histogram + weight bf16 pre-convert (independent of gemm1)
  hipMemsetAsync(deg, 0, (size_t)NN * 4, stream);
  hipMemsetAsync(counter, 0, 16, stream);
  hist_kernel<<<(EE + 255) / 256, 256, 0, stream>>>(dst, deg, W_gat, W_lin,
                                                    Wg16, Wl16);
  alloc_kernel<<<(NN + 255) / 256, 256, 0, stream>>>(deg, rowptr, cur, counter);
  // 1) hb = fp16(x @ W_gat^T) with fused a_s/a_d epilogue  [MFMA]
  gemm_mfma<<<(NN + 63) / 64, 256, 0, stream>>>(x, nullptr, Wg16, nullptr, hb,
                                                nullptr, att_src, att_dst, a_s,
                                                a_d, NN);
  // 2) XCD-range-aligned filter-scan scatter (16 B records)
  scatter_fine<<<NRANGE * P1B, 256, 0, stream>>>(src, dst, a_s, a_d, cur,
                                                 ebuf);
  // 3) softmax-weighted aggregation (+bias, relu) -> bf16
  aggregate_kernel<<<(NN + 3) / 4, 256, 0, stream>>>(
      (const uint4*)hb, a_s, a_d, bias_gat, rowptr, deg, ebuf,
      (uint4*)ob);
  // 4) out = ob @ W_lin^T + b_lin  [MFMA]
  gemm_mfma<<<(NN + 63) / 64, 256, 0, stream>>>(nullptr, ob, Wl16, b_lin,
                                                nullptr, out, nullptr, nullptr,
                                                nullptr, nullptr, NN);
}

// Round 7
// 382.221 us; speedup vs baseline: 6.8640x; 1.1273x over previous
//
#include <hip/hip_runtime.h>
#include <hip/hip_bf16.h>
#include <hip/hip_fp16.h>

// Problem constants (match reference)
#define NN 100000
#define EE 1600000
#define INF_DIM 128
#define NHEAD 4
#define HDIM 32
#define NEG_SLOPE 0.2f

#define GB 768  // persistent gemm grid: 3 blocks/CU x 256 CUs

typedef __attribute__((ext_vector_type(8))) short short8;
typedef __attribute__((ext_vector_type(4))) float floatx4;

__device__ __forceinline__ unsigned short f2bf(float x) {
  union { float f; unsigned int u; } c;
  c.f = x;
  const unsigned int r = c.u + 0x7fffu + ((c.u >> 16) & 1u);  // RNE
  return (unsigned short)(r >> 16);
}
// native packed fp32->bf16 convert (gfx950): D = {bf16(hi), bf16(lo)}
__device__ __forceinline__ unsigned int cvtpk_bf16(float lo, float hi) {
  unsigned int r;
  asm("v_cvt_pk_bf16_f32 %0, %1, %2" : "=v"(r) : "v"(lo), "v"(hi));
  return r;
}
__device__ __forceinline__ unsigned int packh2(float a, float b) {
  const __half ha = __float2half(a), hb = __float2half(b);
  const unsigned short ua = *(const unsigned short*)&ha;
  const unsigned short ub = *(const unsigned short*)&hb;
  return (unsigned int)ua | ((unsigned int)ub << 16);
}
// select fp16 weight for this lane's head out of packed {y=h01, z=h23}
__device__ __forceinline__ float pickw(const int4 e, const int head) {
  const unsigned int d = (head & 2) ? (unsigned int)e.z : (unsigned int)e.y;
  const unsigned short us =
      (head & 1) ? (unsigned short)(d >> 16) : (unsigned short)(d & 0xffffu);
  const __half h = *(const __half*)&us;
  return __half2float(h);
}
// fma 8 fp16 features (one uint4 = 4 half2) into acc[8] with scalar weight c
// (half2->float2 + fmaf fuses to v_fma_mix_f32)
__device__ __forceinline__ void accum8h(const uint4 g, const float c,
                                        float* acc) {
  union { uint4 u; __half2 h[4]; } v;
  v.u = g;
#pragma unroll
  for (int j = 0; j < 4; ++j) {
    const float2 f = __half22float2(v.h[j]);
    acc[2 * j] = fmaf(c, f.x, acc[2 * j]);
    acc[2 * j + 1] = fmaf(c, f.y, acc[2 * j + 1]);
  }
}

// ---------------------------------------------------------------------------
// Persistent MFMA GEMM: C[M,128] = A[M,128] @ W[128,128]^T (+bias).
// Grid = GB blocks (3/CU); each block stages W (fp32 -> bf16 via cvt_pk) to
// LDS ONCE, then loops over 64-row tiles (t = bid; t < ntiles; t += GB).
// A input: fp32 (Af) or fp16 (Ab as raw u16). Output: fp16 (Ch) or fp32+bias
// (Cf). Optional fused work:
//  - dstE != null: dst histogram via fire-and-forget atomicAdd (hidden under
//    staging/MFMA; result consumed only after kernel-end fence).
//  - a_s != null: per-head attention dots from the fp32 accumulators
//    (16 FMA/row + shfl_xor(1..8) intra-16 tree).
// ---------------------------------------------------------------------------
#define LDA 136

__global__ __launch_bounds__(256) void gemm_mfma(
    const float* __restrict__ Af, const unsigned short* __restrict__ Ab,
    const float* __restrict__ W, const float* __restrict__ bias,
    unsigned short* __restrict__ Ch, float* __restrict__ Cf,
    const float* __restrict__ att_src, const float* __restrict__ att_dst,
    float* __restrict__ a_s, float* __restrict__ a_d,
    const int* __restrict__ dstE, int* __restrict__ deg, int M) {
  __shared__ unsigned short sA[64 * LDA];   // [m][k]
  __shared__ unsigned short sW[128 * LDA];  // [o][k] == B^T
  const int tid = threadIdx.x;

  // fused histogram: coalesced dst loads + no-return atomics (fire & forget)
  if (dstE) {
    for (int e = blockIdx.x * 256 + tid; e < EE; e += GB * 256)
      atomicAdd(&deg[dstE[e]], 1);
  }

  {  // W stage once: fp32 -> bf16 (packed cvt), 64 elems/thread
    const int r = tid >> 1;
    const int c0 = (tid & 1) * 64;
#pragma unroll
    for (int j = 0; j < 16; ++j) {
      const float4 v = *(const float4*)&W[r * 128 + c0 + j * 4];
      uint2 u;
      u.x = cvtpk_bf16(v.x, v.y);
      u.y = cvtpk_bf16(v.z, v.w);
      *(uint2*)&sW[r * LDA + c0 + j * 4] = u;
    }
  }

  const int wv = tid >> 6;
  const int lane = tid & 63;
  const int l16 = lane & 15;
  const int quad = lane >> 4;
  const int ntiles = (M + 63) >> 6;

  float avs[8], avd[8];
  if (a_s) {
#pragma unroll
    for (int nt = 0; nt < 8; ++nt) {
      avs[nt] = att_src[nt * 16 + l16];  // flat [h*32+d], col = nt*16+l16
      avd[nt] = att_dst[nt * 16 + l16];
    }
  }

  for (int t = blockIdx.x; t < ntiles; t += GB) {
    const int m0 = t * 64;
    __syncthreads();  // prior iteration's LDS reads done (also orders sW once)
    {
      const int r = tid >> 2;
      const int gm = m0 + r;
      const int c0 = (tid & 3) * 32;
      if (gm < M) {
        if (Af) {
#pragma unroll
          for (int j = 0; j < 8; ++j) {
            const float4 v = *(const float4*)&Af[(size_t)gm * 128 + c0 + j * 4];
            uint2 u;
            u.x = cvtpk_bf16(v.x, v.y);
            u.y = cvtpk_bf16(v.z, v.w);
            *(uint2*)&sA[r * LDA + c0 + j * 4] = u;
          }
        } else {
          // fp16 input: convert to bf16 for the MFMA via float round-trip
#pragma unroll
          for (int j = 0; j < 4; ++j) {
            const uint4 v = *(const uint4*)&Ab[(size_t)gm * 128 + c0 + j * 8];
            union { uint4 u; __half2 h[4]; } hv;
            hv.u = v;
            uint4 o;
            float2 f0 = __half22float2(hv.h[0]);
            float2 f1 = __half22float2(hv.h[1]);
            float2 f2 = __half22float2(hv.h[2]);
            float2 f3 = __half22float2(hv.h[3]);
            o.x = cvtpk_bf16(f0.x, f0.y);
            o.y = cvtpk_bf16(f1.x, f1.y);
            o.z = cvtpk_bf16(f2.x, f2.y);
            o.w = cvtpk_bf16(f3.x, f3.y);
            *(uint4*)&sA[r * LDA + c0 + j * 8] = o;
          }
        }
      } else {
#pragma unroll
        for (int j = 0; j < 4; ++j) {
          uint4 z;
          z.x = z.y = z.z = z.w = 0u;
          *(uint4*)&sA[r * LDA + c0 + j * 8] = z;
        }
      }
    }
    __syncthreads();

    floatx4 acc[8];
#pragma unroll
    for (int i = 0; i < 8; ++i) acc[i] = (floatx4){0.f, 0.f, 0.f, 0.f};

    const unsigned short* aRow = &sA[(wv * 16 + l16) * LDA + quad * 8];
#pragma unroll
    for (int kc = 0; kc < 4; ++kc) {
      const short8 afrag = *(const short8*)(aRow + kc * 32);
#pragma unroll
      for (int nt = 0; nt < 8; ++nt) {
        const short8 bfrag =
            *(const short8*)&sW[(nt * 16 + l16) * LDA + kc * 32 + quad * 8];
        acc[nt] = __builtin_amdgcn_mfma_f32_16x16x32_bf16(afrag, bfrag,
                                                          acc[nt], 0, 0, 0);
      }
    }

    const int mrow = m0 + wv * 16 + quad * 4;
#pragma unroll
    for (int nt = 0; nt < 8; ++nt) {
      const int col = nt * 16 + l16;
      const float bv = Cf ? bias[col] : 0.f;
#pragma unroll
      for (int r = 0; r < 4; ++r) {
        const int gm = mrow + r;
        if (gm < M) {
          const float v = acc[nt][r];
          if (Ch) {
            const __half hh = __float2half(v);
            Ch[(size_t)gm * 128 + col] = *(const unsigned short*)&hh;
          } else {
            Cf[(size_t)gm * 128 + col] = v + bv;
          }
        }
      }
    }

    // fused attention-dot epilogue (gemm1 only)
    if (a_s) {
#pragma unroll
      for (int r = 0; r < 4; ++r) {
        float ps0 = acc[0][r] * avs[0] + acc[1][r] * avs[1];
        float ps1 = acc[2][r] * avs[2] + acc[3][r] * avs[3];
        float ps2 = acc[4][r] * avs[4] + acc[5][r] * avs[5];
        float ps3 = acc[6][r] * avs[6] + acc[7][r] * avs[7];
        float pd0 = acc[0][r] * avd[0] + acc[1][r] * avd[1];
        float pd1 = acc[2][r] * avd[2] + acc[3][r] * avd[3];
        float pd2 = acc[4][r] * avd[4] + acc[5][r] * avd[5];
        float pd3 = acc[6][r] * avd[6] + acc[7][r] * avd[7];
#pragma unroll
        for (int off = 1; off < 16; off <<= 1) {
          ps0 += __shfl_xor(ps0, off);
          ps1 += __shfl_xor(ps1, off);
          ps2 += __shfl_xor(ps2, off);
          ps3 += __shfl_xor(ps3, off);
          pd0 += __shfl_xor(pd0, off);
          pd1 += __shfl_xor(pd1, off);
          pd2 += __shfl_xor(pd2, off);
          pd3 += __shfl_xor(pd3, off);
        }
        const int gm = mrow + r;
        if (gm < M) {
          const int hs = l16 & 3;
          float vs = ps0;
          if (hs == 1) vs = ps1;
          if (hs == 2) vs = ps2;
          if (hs == 3) vs = ps3;
          float vd = pd0;
          if (hs == 1) vd = pd1;
          if (hs == 2) vd = pd2;
          if (hs == 3) vd = pd3;
          if (l16 < 4)
            a_s[gm * 4 + hs] = vs;
          else if (l16 < 8)
            a_d[gm * 4 + hs] = vd;
        }
      }
    }
  }
}

__global__ __launch_bounds__(256) void alloc_kernel(const int* __restrict__ deg,
                                                    int* __restrict__ rowptr,
                                                    int* __restrict__ cur,
                                                    int* __restrict__ counter) {
  const int i = blockIdx.x * blockDim.x + threadIdx.x;
  const int lane = threadIdx.x & 63;
  const int d = (i < NN) ? deg[i] : 0;
  int s = d;
#pragma unroll
  for (int off = 1; off < 64; off <<= 1) {
    const int v = __shfl_up(s, off, 64);
    if (lane >= off) s += v;
  }
  const int total = __shfl(s, 63, 64);
  int base = 0;
  if (lane == 63) base = atomicAdd(counter, total);
  base = __shfl(base, 63, 64);
  const int p = base + s - d;
  if (i < NN) {
    rowptr[i] = p;
    cur[i] = p;
  }
}

// ---------------------------------------------------------------------------
// Scatter: 2 edges per thread (i, i+E/2) for 2x memory-level parallelism.
// Emits 16 B records {src, fp16 w01, fp16 w23, 0} at CSR positions.
// ---------------------------------------------------------------------------
__global__ void scatter_kernel(const int* __restrict__ src,
                               const int* __restrict__ dst,
                               const float* __restrict__ a_s,
                               const float* __restrict__ a_d,
                               int* __restrict__ cur, int4* __restrict__ ebuf) {
  const int iA = blockIdx.x * blockDim.x + threadIdx.x;
  const int iB = iA + (EE / 2);
  const int sA_ = src[iA];
  const int dA = dst[iA];
  const int sB_ = src[iB];
  const int dB = dst[iB];
  const int pA = atomicAdd(&cur[dA], 1);
  const int pB = atomicAdd(&cur[dB], 1);
  const float4 asA = *(const float4*)&a_s[sA_ * 4];
  const float4 adA = *(const float4*)&a_d[dA * 4];
  const float4 asB = *(const float4*)&a_s[sB_ * 4];
  const float4 adB = *(const float4*)&a_d[dB * 4];
  float4 lA, lB;
  lA.x = asA.x + adA.x;
  lA.y = asA.y + adA.y;
  lA.z = asA.z + adA.z;
  lA.w = asA.w + adA.w;
  lB.x = asB.x + adB.x;
  lB.y = asB.y + adB.y;
  lB.z = asB.z + adB.z;
  lB.w = asB.w + adB.w;
  lA.x = lA.x > 0.f ? lA.x : NEG_SLOPE * lA.x;
  lA.y = lA.y > 0.f ? lA.y : NEG_SLOPE * lA.y;
  lA.z = lA.z > 0.f ? lA.z : NEG_SLOPE * lA.z;
  lA.w = lA.w > 0.f ? lA.w : NEG_SLOPE * lA.w;
  lB.x = lB.x > 0.f ? lB.x : NEG_SLOPE * lB.x;
  lB.y = lB.y > 0.f ? lB.y : NEG_SLOPE * lB.y;
  lB.z = lB.z > 0.f ? lB.z : NEG_SLOPE * lB.z;
  lB.w = lB.w > 0.f ? lB.w : NEG_SLOPE * lB.w;
  int4 eA, eB;
  eA.x = sA_;
  eA.y = (int)packh2(__expf(lA.x), __expf(lA.y));
  eA.z = (int)packh2(__expf(lA.z), __expf(lA.w));
  eA.w = 0;
  eB.x = sB_;
  eB.y = (int)packh2(__expf(lB.x), __expf(lB.y));
  eB.z = (int)packh2(__expf(lB.z), __expf(lB.w));
  eB.w = 0;
  ebuf[pA] = eA;
  ebuf[pB] = eB;
}

// ---------------------------------------------------------------------------
// Aggregate: one wave per destination node, quarter-wave per edge.
// q = lane>>4 (edge slot), f = lane&15 (feature group, head = f>>2).
// 16-edge super-iteration: 4 record loads then 4 independent uint4 feature
// gathers in flight (statically unrolled), then consume. Features are fp16
// (v_fma_mix accumulate into fp32). Cross-quarter reduce via shfl_xor(16/32).
// ---------------------------------------------------------------------------
__global__ __launch_bounds__(256) void aggregate_kernel(
    const uint4* __restrict__ hbd4, const float* __restrict__ a_s,
    const float* __restrict__ a_d, const float* __restrict__ bias_gat,
    const int* __restrict__ rowptr, const int* __restrict__ deg,
    const int4* __restrict__ ebuf, uint4* __restrict__ obd4) {
  const int wave = (blockIdx.x * blockDim.x + threadIdx.x) >> 6;
  if (wave >= NN) return;
  const int lane = threadIdx.x & 63;
  const int q = lane >> 4;
  const int f = lane & 15;
  const int head = f >> 2;
  const int n = wave;

  float acc[8];
  float ds;
  {  // self loop (only quarter 0 contributes; others start at zero)
    const float l0 = a_s[n * 4 + head] + a_d[n * 4 + head];
    const float l = fmaxf(l0, NEG_SLOPE * l0);
    float cs = __expf(l);
    if (q != 0) cs = 0.f;
    union { uint4 u; __half2 h[4]; } v;
    v.u = hbd4[(size_t)n * 16 + f];
#pragma unroll
    for (int j = 0; j < 4; ++j) {
      const float2 fv = __half22float2(v.h[j]);
      acc[2 * j] = cs * fv.x;
      acc[2 * j + 1] = cs * fv.y;
    }
    ds = cs;
  }

  const int beg = rowptr[n];
  const int end = beg + deg[n];
  for (int i = beg; i < end; i += 16) {
    int4 e0, e1, e2, e3;
    {
      const int i0 = i + q, i1 = i + 4 + q, i2 = i + 8 + q, i3 = i + 12 + q;
      e0 = ebuf[i0 < end ? i0 : end - 1];
      e1 = ebuf[i1 < end ? i1 : end - 1];
      e2 = ebuf[i2 < end ? i2 : end - 1];
      e3 = ebuf[i3 < end ? i3 : end - 1];
    }
    // 4 independent feature gathers in flight
    const uint4 g0 = hbd4[(size_t)e0.x * 16 + f];
    const uint4 g1 = hbd4[(size_t)e1.x * 16 + f];
    const uint4 g2 = hbd4[(size_t)e2.x * 16 + f];
    const uint4 g3 = hbd4[(size_t)e3.x * 16 + f];
    float c0 = pickw(e0, head);
    float c1 = pickw(e1, head);
    float c2 = pickw(e2, head);
    float c3 = pickw(e3, head);
    if (i + q >= end) c0 = 0.f;
    if (i + 4 + q >= end) c1 = 0.f;
    if (i + 8 + q >= end) c2 = 0.f;
    if (i + 12 + q >= end) c3 = 0.f;
    accum8h(g0, c0, acc);
    accum8h(g1, c1, acc);
    accum8h(g2, c2, acc);
    accum8h(g3, c3, acc);
    ds += c0 + c1 + c2 + c3;
  }

  // reduce across the 4 quarters (lanes l, l^16, l^32, l^48 share f)
#pragma unroll
  for (int j = 0; j < 8; ++j) {
    acc[j] += __shfl_xor(acc[j], 16);
    acc[j] += __shfl_xor(acc[j], 32);
  }
  ds += __shfl_xor(ds, 16);
  ds += __shfl_xor(ds, 32);

  if (q == 0) {
    const float inv = 1.0f / ds;
    const float4 b0 = *(const float4*)&bias_gat[f * 8];
    const float4 b1 = *(const float4*)&bias_gat[f * 8 + 4];
    float v0 = acc[0] * inv + b0.x;
    float v1 = acc[1] * inv + b0.y;
    float v2 = acc[2] * inv + b0.z;
    float v3 = acc[3] * inv + b0.w;
    float v4 = acc[4] * inv + b1.x;
    float v5 = acc[5] * inv + b1.y;
    float v6 = acc[6] * inv + b1.z;
    float v7 = acc[7] * inv + b1.w;
    v0 = v0 > 0.f ? v0 : 0.f;
    v1 = v1 > 0.f ? v1 : 0.f;
    v2 = v2 > 0.f ? v2 : 0.f;
    v3 = v3 > 0.f ? v3 : 0.f;
    v4 = v4 > 0.f ? v4 : 0.f;
    v5 = v5 > 0.f ? v5 : 0.f;
    v6 = v6 > 0.f ? v6 : 0.f;
    v7 = v7 > 0.f ? v7 : 0.f;
    // aggregate output stored as fp16 (consumed by gemm2's Ab path)
    uint4 r;
    r.x = packh2(v0, v1);
    r.y = packh2(v2, v3);
    r.z = packh2(v4, v5);
    r.w = packh2(v6, v7);
    obd4[(size_t)n * 16 + f] = r;
  }
}

// ---------------------------------------------------------------------------
extern "C" void kernel_launch(void* const* d_in, const int* in_sizes, int n_in,
                              void* d_out, int out_size, void* d_ws,
                              size_t ws_size, hipStream_t stream) {
  const float* x = (const float*)d_in[0];
  const int* ei = (const int*)d_in[1];  // [2,E]: row0=src, row1=dst
  const float* W_gat = (const float*)d_in[2];
  const float* att_src = (const float*)d_in[3];
  const float* att_dst = (const float*)d_in[4];
  const float* bias_gat = (const float*)d_in[5];
  const float* W_lin = (const float*)d_in[6];
  const float* b_lin = (const float*)d_in[7];
  float* out = (float*)d_out;

  // workspace carve-up (16B aligned)
  char* ws = (char*)d_ws;
  size_t off = 0;
  unsigned short* hb = (unsigned short*)(ws + off);
  off += (size_t)NN * 128 * 2;  // 25.6 MB (fp16 features)
  unsigned short* ob = (unsigned short*)(ws + off);
  off += (size_t)NN * 128 * 2;  // 25.6 MB (fp16 aggregate out)
  float* a_s = (float*)(ws + off); off += (size_t)NN * 4 * 4;
  float* a_d = (float*)(ws + off); off += (size_t)NN * 4 * 4;
  int* deg = (int*)(ws + off); off += (size_t)NN * 4;
  int* rowptr = (int*)(ws + off); off += (size_t)(NN + 4) * 4;
  int* cur = (int*)(ws + off); off += (size_t)NN * 4;
  int* counter = (int*)(ws + off); off += 16;
  int4* ebuf = (int4*)(ws + off); off += (size_t)EE * 16;  // 25.6 MB

  const int* src = ei;
  const int* dst = ei + EE;

  hipMemsetAsync(deg, 0, (size_t)NN * 4, stream);
  hipMemsetAsync(counter, 0, 16, stream);
  // 1) hb = fp16(x @ W_gat^T) with fused a_s/a_d epilogue AND fused dst
  //    histogram (fire-and-forget atomics)  [MFMA, persistent blocks]
  gemm_mfma<<<GB, 256, 0, stream>>>(x, nullptr, W_gat, nullptr, hb, nullptr,
                                    att_src, att_dst, a_s, a_d, dst, deg, NN);
  // 2) CSR offsets
  alloc_kernel<<<(NN + 255) / 256, 256, 0, stream>>>(deg, rowptr, cur, counter);
  // 3) scatter with fused edge-record precompute (16 B records, 2 edges/thr)
  scatter_kernel<<<(EE / 2 + 255) / 256, 256, 0, stream>>>(src, dst, a_s, a_d,
                                                           cur, ebuf);
  // 4) softmax-weighted aggregation (+bias, relu) -> fp16
  aggregate_kernel<<<(NN + 3) / 4, 256, 0, stream>>>(
      (const uint4*)hb, a_s, a_d, bias_gat, rowptr, deg, ebuf,
      (uint4*)ob);
  // 5) out = ob @ W_lin^T + b_lin  [MFMA, persistent blocks]
  gemm_mfma<<<GB, 256, 0, stream>>>(nullptr, ob, W_lin, b_lin, nullptr, out,
                                    nullptr, nullptr, nullptr, nullptr,
                                    nullptr, nullptr, NN);
}